// Round 4
// baseline (122.717 us; speedup 1.0000x reference)
//
#include <hip/hip_runtime.h>
#include <math.h>

#define NV 720
#define NU 736
#define NUP 768      // padded Q row stride (bins 736..767 never gathered)
#define NXY 512

__device__ __forceinline__ float rl(float v, int l) {
    return __int_as_float(__builtin_amdgcn_readlane(__float_as_int(v), l));
}
#define KEEP(x) asm volatile("" : "+v"(x))

// ---------------- Stage 1+2: cosine weight + Ram-Lak Toeplitz (+ trig, + out=0) --------
// R20 = R19 bugfix (resubmitted after R3 infra timeout). R19's readlane-broadcast filter
// failed: the svA/svB chunk loads were sunk by the compiler under the divergent
// `if (J0 < 92)` guard, so in wave 1 of each tap group (active lanes 0..27 only) lanes
// 28..63 never loaded -> readlane returned garbage. Fix: tap loop runs under FULL exec
// (lanes J0>=92 compute throwaway accs with a clamped in-bounds weight base), loads
// pinned with asm keep-alives. Stores still J0<92-guarded. Numerics for live threads
// bit-identical to R18 (ascending-m chunk order, double wco).
// Theory (unchanged): sv broadcast is wave-uniform -> v_readlane (VALU, 4 pipes/CU)
// instead of DS; one ds_read2_b32 feeds 8 FMAs; grid 720 -> CU imbalance 1.07.
__global__ __launch_bounds__(512, 6) void filter_kernel(const float* __restrict__ sino,
                                                        float* __restrict__ Q,
                                                        float4* __restrict__ trig,
                                                        float* __restrict__ out_zero) {
    __shared__ float s4[2][368][4];   // [parity][m][view]  (11.8 KB)
    __shared__ float wco[736];        // wco[i] = -1/(pi*(2i-735)*DU)^2  (2.9 KB)
    __shared__ float part[3][128][8]; // partials from tap-groups 1..3  (12.3 KB)
    const int bx = blockIdx.x;
    const int q = bx & 3;             // output quadrant: r = q
    const int vb = bx >> 2;
    const int v0 = vb * 4;
    const int tid = threadIdx.x;      // [0,512)
    const int tz = tid >> 7;          // tap group [0,4): taps [92*tz, 92*tz+92)
    const int tg = tid & 127;         // role within group; J0 = tg, outputs if < 92
    const int lane = tid & 63;        // wave-local lane (readlane source mapping)

    // zero the atomic target (replaces the hipMemsetAsync dispatch; bp launches after)
    for (int i = bx * 512 + tid; i < NXY * NXY; i += 720 * 512)
        out_zero[i] = 0.0f;

    if (q == 0 && tid < 4) {
        int v = v0 + tid;
        float beta = (float)((double)v * (2.0 * M_PI / 720.0));
        float cb = cosf(beta), sb = sinf(beta);
        const float K = (float)(1085.6 / 1.2858);   // DSD/DU
        trig[v] = make_float4(cb * K, sb * K, cb, sb);
    }
    for (int i = tid; i < 736; i += 512) {
        double n = (double)(2 * i - 735);
        double a = M_PI * n * 1.2858;
        wco[i] = (float)(-1.0 / (a * a));
    }
    const float DSD2 = (float)(1085.6 * 1085.6);
    // group tz stages view tz (128 threads each)
    for (int u = tg; u < 736; u += 128) {
        float us = ((float)u - 367.5f) * 1.2858f;
        float cw = 1085.6f / sqrtf(DSD2 + us * us);
        s4[u & 1][u >> 1][tz] = sino[(v0 + tz) * NU + u] * cw;
    }
    __syncthreads();

    const int m0 = 92 * tz;
    // per-lane sample chunks for readlane broadcast. Loaded under FULL exec (no branch
    // between here and the tap loop) -- every lane's register is a readlane source.
    const int iA = m0 + lane;                   // <= 339, in bounds
    const int iB = min(m0 + 64 + lane, 367);    // clamp: only lanes<28 are consumed
    float4 svA0 = *(const float4*)&s4[0][iA][0];
    float4 svA1 = *(const float4*)&s4[1][iA][0];
    float4 svB0 = *(const float4*)&s4[0][iB][0];
    float4 svB1 = *(const float4*)&s4[1][iB][0];
    KEEP(svA0.x); KEEP(svA0.y); KEEP(svA0.z); KEEP(svA0.w);
    KEEP(svA1.x); KEEP(svA1.y); KEEP(svA1.z); KEEP(svA1.w);
    KEEP(svB0.x); KEEP(svB0.y); KEEP(svB0.z); KEEP(svB0.w);
    KEEP(svB1.x); KEEP(svB1.y); KEEP(svB1.z); KEEP(svB1.w);

    float a00 = 0.f, a01 = 0.f, a02 = 0.f, a03 = 0.f;   // pj=0, views 0..3
    float a10 = 0.f, a11 = 0.f, a12 = 0.f, a13 = 0.f;   // pj=1, views 0..3
    const int J0 = tg;
    const int J0c = min(J0, 91);            // threads J0>=92: throwaway but in-bounds

    {
        const int K0 = J0c + 92 * q + 367;  // weight base: wco[K0-m] (pj=0), +1 (pj=1)
        const float* wpA = &wco[K0 - m0];
        #pragma unroll 4
        for (int mm = 0; mm < 64; ++mm) {   // m = m0 + mm, ascending (order == R18)
            const float* p = wpA - mm;
            const float w0 = p[0];          // ds_read2_b32 (fused pair)
            const float w1 = p[1];
            const float s1x = rl(svA1.x, mm), s1y = rl(svA1.y, mm),
                        s1z = rl(svA1.z, mm), s1w = rl(svA1.w, mm);
            const float s0x = rl(svA0.x, mm), s0y = rl(svA0.y, mm),
                        s0z = rl(svA0.z, mm), s0w = rl(svA0.w, mm);
            a00 = fmaf(w0, s1x, a00); a01 = fmaf(w0, s1y, a01);
            a02 = fmaf(w0, s1z, a02); a03 = fmaf(w0, s1w, a03);
            a10 = fmaf(w1, s0x, a10); a11 = fmaf(w1, s0y, a11);
            a12 = fmaf(w1, s0z, a12); a13 = fmaf(w1, s0w, a13);
        }
        const float* wpB = wpA - 64;
        #pragma unroll 4
        for (int mm = 0; mm < 28; ++mm) {   // m = m0 + 64 + mm, ascending
            const float* p = wpB - mm;
            const float w0 = p[0];
            const float w1 = p[1];
            const float s1x = rl(svB1.x, mm), s1y = rl(svB1.y, mm),
                        s1z = rl(svB1.z, mm), s1w = rl(svB1.w, mm);
            const float s0x = rl(svB0.x, mm), s0y = rl(svB0.y, mm),
                        s0z = rl(svB0.z, mm), s0w = rl(svB0.w, mm);
            a00 = fmaf(w0, s1x, a00); a01 = fmaf(w0, s1y, a01);
            a02 = fmaf(w0, s1z, a02); a03 = fmaf(w0, s1w, a03);
            a10 = fmaf(w1, s0x, a10); a11 = fmaf(w1, s0y, a11);
            a12 = fmaf(w1, s0z, a12); a13 = fmaf(w1, s0w, a13);
        }
    }

    if (tz != 0 && J0 < 92) {
        *(float4*)&part[tz - 1][J0][0] = make_float4(a00, a01, a02, a03);
        *(float4*)&part[tz - 1][J0][4] = make_float4(a10, a11, a12, a13);
    }
    __syncthreads();

    if (tz == 0 && J0 < 92) {
        // combine in m-order: chunk0 (regs) + chunk1 + chunk2 + chunk3 (== R18 order)
        #pragma unroll
        for (int g = 0; g < 3; ++g) {
            const float4 p0 = *(const float4*)&part[g][J0][0];
            const float4 p1 = *(const float4*)&part[g][J0][4];
            a00 += p0.x; a01 += p0.y; a02 += p0.z; a03 += p0.w;
            a10 += p1.x; a11 += p1.y; a12 += p1.z; a13 += p1.w;
        }
        const float H0 = (float)(1.0 / (4.0 * 1.2858 * 1.2858));
        const int jh = J0 + 92 * q;
        const float4 c0 = *(const float4*)&s4[0][jh][0];   // center, pj=0 (parity 0)
        const float4 c1 = *(const float4*)&s4[1][jh][0];   // center, pj=1 (parity 1)
        a00 = fmaf(H0, c0.x, a00); a01 = fmaf(H0, c0.y, a01);
        a02 = fmaf(H0, c0.z, a02); a03 = fmaf(H0, c0.w, a03);
        a10 = fmaf(H0, c1.x, a10); a11 = fmaf(H0, c1.y, a11);
        a12 = fmaf(H0, c1.z, a12); a13 = fmaf(H0, c1.w, a13);
        const int j0i = 2 * jh;
        const float DU = 1.2858f;
        Q[(v0 + 0) * NUP + j0i] = a00 * DU;  Q[(v0 + 0) * NUP + j0i + 1] = a10 * DU;
        Q[(v0 + 1) * NUP + j0i] = a01 * DU;  Q[(v0 + 1) * NUP + j0i + 1] = a11 * DU;
        Q[(v0 + 2) * NUP + j0i] = a02 * DU;  Q[(v0 + 2) * NUP + j0i + 1] = a12 * DU;
        Q[(v0 + 3) * NUP + j0i] = a03 * DU;  Q[(v0 + 3) * NUP + j0i + 1] = a13 * DU;
    }
}

// ---------------- Stage 3: backprojection — R15 VERBATIM (54.5us, passed) --------------
// R16 lesson: address-dependent VMEM in the hot loop exposes ~200cyc L2 latency per
// iter (70us regression) — only pre-staged LDS fetches belong in the gather loop.
// R14: DS-crossbar is the binding resource; ds_read2 per bilinear gather. R15: dbuf.
// Lessons: no gate-chain reassociation (R4); 1 px/lane (R5); no branch-wrapped or
// address-dependent in-loop VMEM (R12/R16).
__global__ __launch_bounds__(256) void bp_kernel(const float* __restrict__ Q,
                                                 const float4* __restrict__ trig,
                                                 float* __restrict__ out) {
    __shared__ float win[2][4][NUP];          // 24 KB double buffer
    const int b = blockIdx.x;
    const int c = b & 15;                     // view chunk: base views {c, c+16, ...}
    const int blk = b >> 4;                   // 256 quadrant blocks of 16x16
    const int bx = blk >> 4;
    const int by = blk & 15;
    const int t = threadIdx.x;
    const int w = t >> 6;
    const int l = t & 63;
    const int iq = (bx << 4) + ((w >> 1) << 3) + (l >> 3);   // [0,256)
    const int jq = (by << 4) + ((w & 1) << 3) + (l & 7);     // [0,256)

    const float dx = 400.0f / 512.0f;         // 0.78125 exact
    const float X = ((float)iq - 255.5f) * dx;   // < 0
    const float Y = ((float)jq - 255.5f) * dx;   // < 0
    const float Kc = (float)(1085.6 / 1.2858);

    float acc0 = 0.0f, acc1 = 0.0f, acc2 = 0.0f, acc3 = 0.0f;
    const bool inr = fmaf(X, X, Y * Y) <= 236.5f * 236.5f;
    const bool myint = __all(inr);

    const int nk = (c < 4) ? 12 : 11;         // ceil((180-c)/16)
    const float* rowp = Q + (size_t)(c + 180 * w) * NUP;   // wave w stages row w
    const float4* tvp = trig + c;

    // preload iter 0 into buffer 0
    #pragma unroll
    for (int ch = 0; ch < 3; ++ch)
        __builtin_amdgcn_global_load_lds(
            (const __attribute__((address_space(1))) void*)(rowp + ch * 256 + l * 4),
            (__attribute__((address_space(3))) void*)&win[0][w][ch * 256],
            16, 0, 0);

    for (int it = 0; it < nk; ++it) {
        __syncthreads();                      // win[it&1] staged; prior reads of it^1 done
        if (it + 1 < nk) {
            const float* rn = rowp + 16 * NUP;
            #pragma unroll
            for (int ch = 0; ch < 3; ++ch)
                __builtin_amdgcn_global_load_lds(
                    (const __attribute__((address_space(1))) void*)(rn + ch * 256 + l * 4),
                    (__attribute__((address_space(3))) void*)&win[(it + 1) & 1][w][ch * 256],
                    16, 0, 0);
        }
        const float* winf = &win[it & 1][0][0];

        if (myint) {
            // ---- interior: symmetric geometry (R10-proven), ds_read2 gathers ---------
            const float4 tv = tvp[0];                     // cb = tv.z, sb = tv.w
            float a = fmaf(tv.z, X, tv.w * Y);            // t0
            float bb = fmaf(tv.z, Y, -tv.w * X);          // s0
            float aK = a * Kc, bK = bb * Kc;
            float D0 = 595.0f - bb, D1 = 595.0f + a, D2 = 595.0f + bb, D3 = 595.0f - a;
            float r0 = __builtin_amdgcn_rcpf(D0);
            float r1 = __builtin_amdgcn_rcpf(D1);
            float r2 = __builtin_amdgcn_rcpf(D2);
            float r3 = __builtin_amdgcn_rcpf(D3);
            float fi0 = fmaf(aK,  r0, 367.5f);
            float fi1 = fmaf(bK,  r1, 367.5f);
            float fi2 = fmaf(-aK, r2, 367.5f);
            float fi3 = fmaf(-bK, r3, 367.5f);
            int im[4] = {(int)fi0, (int)fi1, (int)fi2, (int)fi3};  // in [1,733]
            float ff[4] = {__builtin_amdgcn_fractf(fi0), __builtin_amdgcn_fractf(fi1),
                           __builtin_amdgcn_fractf(fi2), __builtin_amdgcn_fractf(fi3)};
            float gg[4] = {r0 * r0, r1 * r1, r2 * r2, r3 * r3};
            float* accp[4] = {&acc0, &acc1, &acc2, &acc3};
            #pragma unroll
            for (int m = 0; m < 4; ++m) {
                #pragma unroll
                for (int k = 0; k < 4; ++k) {
                    const float* p = winf + (k * NUP + im[m]);
                    float q0 = p[0];                      // ds_read2_b32 (fused pair)
                    float q1 = p[1];
                    float val = fmaf(ff[m], q1 - q0, q0);
                    *accp[(m - k) & 3] = fmaf(gg[m], val, *accp[(m - k) & 3]);
                }
            }
        } else {
            // ---- exterior: R3-exact chains/gates per pixel, staged ds_read2 fetch ----
            const float4 tvs[4] = {tvp[0], tvp[180], tvp[360], tvp[540]};
            const float pX[4] = {X, Y, -X, -Y};
            const float pY[4] = {Y, -X, -Y, X};
            float* accp[4] = {&acc0, &acc1, &acc2, &acc3};
            #pragma unroll
            for (int j = 0; j < 4; ++j) {
                float Xm = pX[j], Ym = pY[j];
                #pragma unroll
                for (int k = 0; k < 4; ++k) {
                    const float4 tv = tvs[k];
                    float t2 = fmaf(tv.x, Xm, tv.y * Ym);               // R3-exact
                    float D  = fmaf(tv.w, Xm, fmaf(tv.z, -Ym, 595.0f)); // R3-exact
                    float rD = __builtin_amdgcn_rcpf(D);
                    float fidx = fmaf(t2, rD, 367.5f);
                    int i0c = min(max((int)fidx, 0), NU - 2);           // v_med3_i32
                    float f = __builtin_amdgcn_fractf(fidx);
                    const float* p = winf + (k * NUP + i0c);
                    float q0 = p[0];                                    // ds_read2_b32
                    float q1 = p[1];
                    float val = fmaf(f, q1 - q0, q0);
                    float cen = fidx - 367.5f;                          // R3-exact gate
                    float g = (__builtin_fabsf(cen) <= 367.5f) ? rD * rD : 0.0f;
                    *accp[j] = fmaf(g, val, *accp[j]);
                }
            }
        }
        rowp += 16 * NUP;
        tvp += 16;
    }
    const float SC = (float)(595.0 * 595.0 * 0.5 * (2.0 * M_PI / 720.0));
    const int ir = 511 - iq, jr = 511 - jq;
    unsafeAtomicAdd(&out[iq * NXY + jq], acc0 * SC);   // P0 = (iq, jq)
    unsafeAtomicAdd(&out[jq * NXY + ir], acc1 * SC);   // P1 = (jq, 511-iq)
    unsafeAtomicAdd(&out[ir * NXY + jr], acc2 * SC);   // P2 = (511-iq, 511-jq)
    unsafeAtomicAdd(&out[jr * NXY + iq], acc3 * SC);   // P3 = (511-jq, iq)
}

extern "C" void kernel_launch(void* const* d_in, const int* in_sizes, int n_in,
                              void* d_out, int out_size, void* d_ws, size_t ws_size,
                              hipStream_t stream) {
    const float* sino = (const float*)d_in[0];
    float* out = (float*)d_out;
    float* Q = (float*)d_ws;                                           // 720*768*4 = 2.21 MB
    float4* trig = (float4*)((char*)d_ws + (size_t)NV * NUP * sizeof(float)); // 16B-aligned

    filter_kernel<<<720, 512, 0, stream>>>(sino, Q, trig, out);        // also zeroes out
    bp_kernel<<<4096, 256, 0, stream>>>(Q, trig, out);
}

// Round 5
// 117.504 us; speedup vs baseline: 1.0444x; 1.0444x over previous
//
#include <hip/hip_runtime.h>
#include <math.h>

#define NV 720
#define NU 736
#define NUP 768      // padded Q row stride (bins 736..767 never gathered)
#define NXY 512
#define NM 368       // detector-bin pairs per view (u = 2m + pu)

// ---------------- Stage 0 (R21): prep — cosine-weight + interleave sino, trig, out=0 ---
// Writes swI[vb][m][pu][vv] = sino[4vb+vv][2m+pu] * cw(2m+pu)  (8 contiguous floats per
// (vb,m) tap -> one s_load_dwordx8 in the filter). Same fp32 ops as the old LDS staging
// -> bit-identical operand values. Also computes trig[] and zeroes the atomic target.
__global__ __launch_bounds__(368) void prep_kernel(const float* __restrict__ sino,
                                                   float* __restrict__ swI,
                                                   float4* __restrict__ trig,
                                                   float* __restrict__ out_zero) {
    const int v = blockIdx.x;         // [0,720)
    const int m = threadIdx.x;        // [0,368)
    const int vb = v >> 2, vv = v & 3;
    const float DSD2 = (float)(1085.6 * 1085.6);
    #pragma unroll
    for (int pu = 0; pu < 2; ++pu) {
        const int u = 2 * m + pu;
        float us = ((float)u - 367.5f) * 1.2858f;
        float cw = 1085.6f / sqrtf(DSD2 + us * us);
        swI[((size_t)vb * NM + m) * 8 + pu * 4 + vv] = sino[v * NU + u] * cw;
    }
    if (m == 0) {
        float beta = (float)((double)v * (2.0 * M_PI / 720.0));
        float cb = cosf(beta), sb = sinf(beta);
        const float K = (float)(1085.6 / 1.2858);   // DSD/DU
        trig[v] = make_float4(cb * K, sb * K, cb, sb);
    }
    // zero the atomic target (bp launches after; stream-ordered)
    for (int i = v * 368 + m; i < NXY * NXY; i += 720 * 368)
        out_zero[i] = 0.0f;
}

// ---------------- Stage 1+2 (R21): Ram-Lak Toeplitz with scalar-pipe samples ----------
// R20 lesson: readlane broadcast costs VALU issue + SGPR serialization (+11us). R18
// lesson: more waves alone doesn't help (-4us). The tap loop's bottleneck is per-iter
// operand-fetch issue/latency. R21 moves the wave-uniform sample fetch to the SCALAR
// pipe (s_load_dwordx8 from swI; uniformity forced via readfirstlane(m0)) and merges
// both parities per thread so the two weights are LDS-adjacent: per iter = 1 ds_read2_b32
// + 8 scalar floats + 8 FMAs. Grid 720 = 180 vgroups x 4 r-quadrants (imbalance 1.07).
// Per-output summation: ascending m, 4 chunks (92 taps) combined ascending, center tap
// last, *DU last — bit-identical to R18's Q.
__global__ __launch_bounds__(512) void filter_kernel(const float* __restrict__ swI,
                                                     float* __restrict__ Q) {
    __shared__ float wco[736];        // wco[i] = -1/(pi*(2i-735)*DU)^2
    __shared__ float part[3][8][96];  // [chunk-1][comp][J0] partials, stride-1 lanes
    const int bx = blockIdx.x;
    const int q = bx & 3;             // output quadrant: r = q
    const int vb = bx >> 2;
    const int v0 = vb * 4;
    const int tid = threadIdx.x;      // [0,512)
    const int J0 = tid & 127;         // output slot; active if < 92

    for (int i = tid; i < 736; i += 512) {
        double n = (double)(2 * i - 735);
        double a = M_PI * n * 1.2858;
        wco[i] = (float)(-1.0 / (a * a));
    }
    __syncthreads();

    // m0 is wave-uniform (waves never straddle a 128-thread group); readfirstlane makes
    // the compiler SEE it as uniform so sample loads become s_load_* (scalar pipe).
    const int m0 = __builtin_amdgcn_readfirstlane(92 * (tid >> 7));
    const int tz = m0 / 92;           // tap chunk [0,4)
    const float* sw = swI + (size_t)vb * NM * 8;
    const float* sp = sw + (size_t)m0 * 8;

    // accumulators: [pj][view]
    float a00 = 0.f, a01 = 0.f, a02 = 0.f, a03 = 0.f;   // pj=0
    float a10 = 0.f, a11 = 0.f, a12 = 0.f, a13 = 0.f;   // pj=1
    const int J0c = min(J0, 91);      // lanes J0>=92: throwaway, in-bounds (uniform CF)
    const int y0 = J0c + 367 + 92 * q;                   // weight idx y = y0 - m
    const float* wp = &wco[y0 - m0];

    #pragma unroll 4
    for (int mm = 0; mm < 92; ++mm) {                    // m = m0+mm ascending (R18 order)
        const float w0 = wp[-mm];                        // pj=0 weight  } one
        const float w1 = wp[1 - mm];                     // pj=1 weight  } ds_read2_b32
        const float* s = sp + mm * 8;                    // scalar loads (uniform addr)
        const float s10 = s[4], s11 = s[5], s12 = s[6], s13 = s[7];  // pu=1 (for pj=0)
        const float s00 = s[0], s01 = s[1], s02 = s[2], s03 = s[3];  // pu=0 (for pj=1)
        a00 = fmaf(w0, s10, a00); a01 = fmaf(w0, s11, a01);
        a02 = fmaf(w0, s12, a02); a03 = fmaf(w0, s13, a03);
        a10 = fmaf(w1, s00, a10); a11 = fmaf(w1, s01, a11);
        a12 = fmaf(w1, s02, a12); a13 = fmaf(w1, s03, a13);
    }

    if (tz != 0 && J0 < 92) {
        part[tz - 1][0][J0] = a00; part[tz - 1][1][J0] = a01;
        part[tz - 1][2][J0] = a02; part[tz - 1][3][J0] = a03;
        part[tz - 1][4][J0] = a10; part[tz - 1][5][J0] = a11;
        part[tz - 1][6][J0] = a12; part[tz - 1][7][J0] = a13;
    }
    __syncthreads();

    if (tz == 0 && J0 < 92) {
        #pragma unroll
        for (int g = 0; g < 3; ++g) {                    // chunks ascending (R18 order)
            a00 += part[g][0][J0]; a01 += part[g][1][J0];
            a02 += part[g][2][J0]; a03 += part[g][3][J0];
            a10 += part[g][4][J0]; a11 += part[g][5][J0];
            a12 += part[g][6][J0]; a13 += part[g][7][J0];
        }
        const float H0 = (float)(1.0 / (4.0 * 1.2858 * 1.2858));
        const int mc = J0 + 92 * q;                      // center tap: u = j
        const float4 c0 = *(const float4*)(sw + (size_t)mc * 8);      // pu=0 (pj=0)
        const float4 c1 = *(const float4*)(sw + (size_t)mc * 8 + 4);  // pu=1 (pj=1)
        a00 = fmaf(H0, c0.x, a00); a01 = fmaf(H0, c0.y, a01);
        a02 = fmaf(H0, c0.z, a02); a03 = fmaf(H0, c0.w, a03);
        a10 = fmaf(H0, c1.x, a10); a11 = fmaf(H0, c1.y, a11);
        a12 = fmaf(H0, c1.z, a12); a13 = fmaf(H0, c1.w, a13);
        const int j0i = 2 * (J0 + 92 * q);
        const float DU = 1.2858f;
        *(float2*)&Q[(v0 + 0) * NUP + j0i] = make_float2(a00 * DU, a10 * DU);
        *(float2*)&Q[(v0 + 1) * NUP + j0i] = make_float2(a01 * DU, a11 * DU);
        *(float2*)&Q[(v0 + 2) * NUP + j0i] = make_float2(a02 * DU, a12 * DU);
        *(float2*)&Q[(v0 + 3) * NUP + j0i] = make_float2(a03 * DU, a13 * DU);
    }
}

// ---------------- Stage 3: backprojection — R15 VERBATIM (54.5us, passed) --------------
// R16 lesson: address-dependent VMEM in the hot loop exposes ~200cyc L2 latency per
// iter (70us regression) — only pre-staged LDS fetches belong in the gather loop.
// R14: DS-crossbar is the binding resource; ds_read2 per bilinear gather. R15: dbuf.
// Lessons: no gate-chain reassociation (R4); 1 px/lane (R5); no branch-wrapped or
// address-dependent in-loop VMEM (R12/R16).
__global__ __launch_bounds__(256) void bp_kernel(const float* __restrict__ Q,
                                                 const float4* __restrict__ trig,
                                                 float* __restrict__ out) {
    __shared__ float win[2][4][NUP];          // 24 KB double buffer
    const int b = blockIdx.x;
    const int c = b & 15;                     // view chunk: base views {c, c+16, ...}
    const int blk = b >> 4;                   // 256 quadrant blocks of 16x16
    const int bx = blk >> 4;
    const int by = blk & 15;
    const int t = threadIdx.x;
    const int w = t >> 6;
    const int l = t & 63;
    const int iq = (bx << 4) + ((w >> 1) << 3) + (l >> 3);   // [0,256)
    const int jq = (by << 4) + ((w & 1) << 3) + (l & 7);     // [0,256)

    const float dx = 400.0f / 512.0f;         // 0.78125 exact
    const float X = ((float)iq - 255.5f) * dx;   // < 0
    const float Y = ((float)jq - 255.5f) * dx;   // < 0
    const float Kc = (float)(1085.6 / 1.2858);

    float acc0 = 0.0f, acc1 = 0.0f, acc2 = 0.0f, acc3 = 0.0f;
    const bool inr = fmaf(X, X, Y * Y) <= 236.5f * 236.5f;
    const bool myint = __all(inr);

    const int nk = (c < 4) ? 12 : 11;         // ceil((180-c)/16)
    const float* rowp = Q + (size_t)(c + 180 * w) * NUP;   // wave w stages row w
    const float4* tvp = trig + c;

    // preload iter 0 into buffer 0
    #pragma unroll
    for (int ch = 0; ch < 3; ++ch)
        __builtin_amdgcn_global_load_lds(
            (const __attribute__((address_space(1))) void*)(rowp + ch * 256 + l * 4),
            (__attribute__((address_space(3))) void*)&win[0][w][ch * 256],
            16, 0, 0);

    for (int it = 0; it < nk; ++it) {
        __syncthreads();                      // win[it&1] staged; prior reads of it^1 done
        if (it + 1 < nk) {
            const float* rn = rowp + 16 * NUP;
            #pragma unroll
            for (int ch = 0; ch < 3; ++ch)
                __builtin_amdgcn_global_load_lds(
                    (const __attribute__((address_space(1))) void*)(rn + ch * 256 + l * 4),
                    (__attribute__((address_space(3))) void*)&win[(it + 1) & 1][w][ch * 256],
                    16, 0, 0);
        }
        const float* winf = &win[it & 1][0][0];

        if (myint) {
            // ---- interior: symmetric geometry (R10-proven), ds_read2 gathers ---------
            const float4 tv = tvp[0];                     // cb = tv.z, sb = tv.w
            float a = fmaf(tv.z, X, tv.w * Y);            // t0
            float bb = fmaf(tv.z, Y, -tv.w * X);          // s0
            float aK = a * Kc, bK = bb * Kc;
            float D0 = 595.0f - bb, D1 = 595.0f + a, D2 = 595.0f + bb, D3 = 595.0f - a;
            float r0 = __builtin_amdgcn_rcpf(D0);
            float r1 = __builtin_amdgcn_rcpf(D1);
            float r2 = __builtin_amdgcn_rcpf(D2);
            float r3 = __builtin_amdgcn_rcpf(D3);
            float fi0 = fmaf(aK,  r0, 367.5f);
            float fi1 = fmaf(bK,  r1, 367.5f);
            float fi2 = fmaf(-aK, r2, 367.5f);
            float fi3 = fmaf(-bK, r3, 367.5f);
            int im[4] = {(int)fi0, (int)fi1, (int)fi2, (int)fi3};  // in [1,733]
            float ff[4] = {__builtin_amdgcn_fractf(fi0), __builtin_amdgcn_fractf(fi1),
                           __builtin_amdgcn_fractf(fi2), __builtin_amdgcn_fractf(fi3)};
            float gg[4] = {r0 * r0, r1 * r1, r2 * r2, r3 * r3};
            float* accp[4] = {&acc0, &acc1, &acc2, &acc3};
            #pragma unroll
            for (int m = 0; m < 4; ++m) {
                #pragma unroll
                for (int k = 0; k < 4; ++k) {
                    const float* p = winf + (k * NUP + im[m]);
                    float q0 = p[0];                      // ds_read2_b32 (fused pair)
                    float q1 = p[1];
                    float val = fmaf(ff[m], q1 - q0, q0);
                    *accp[(m - k) & 3] = fmaf(gg[m], val, *accp[(m - k) & 3]);
                }
            }
        } else {
            // ---- exterior: R3-exact chains/gates per pixel, staged ds_read2 fetch ----
            const float4 tvs[4] = {tvp[0], tvp[180], tvp[360], tvp[540]};
            const float pX[4] = {X, Y, -X, -Y};
            const float pY[4] = {Y, -X, -Y, X};
            float* accp[4] = {&acc0, &acc1, &acc2, &acc3};
            #pragma unroll
            for (int j = 0; j < 4; ++j) {
                float Xm = pX[j], Ym = pY[j];
                #pragma unroll
                for (int k = 0; k < 4; ++k) {
                    const float4 tv = tvs[k];
                    float t2 = fmaf(tv.x, Xm, tv.y * Ym);               // R3-exact
                    float D  = fmaf(tv.w, Xm, fmaf(tv.z, -Ym, 595.0f)); // R3-exact
                    float rD = __builtin_amdgcn_rcpf(D);
                    float fidx = fmaf(t2, rD, 367.5f);
                    int i0c = min(max((int)fidx, 0), NU - 2);           // v_med3_i32
                    float f = __builtin_amdgcn_fractf(fidx);
                    const float* p = winf + (k * NUP + i0c);
                    float q0 = p[0];                                    // ds_read2_b32
                    float q1 = p[1];
                    float val = fmaf(f, q1 - q0, q0);
                    float cen = fidx - 367.5f;                          // R3-exact gate
                    float g = (__builtin_fabsf(cen) <= 367.5f) ? rD * rD : 0.0f;
                    *accp[j] = fmaf(g, val, *accp[j]);
                }
            }
        }
        rowp += 16 * NUP;
        tvp += 16;
    }
    const float SC = (float)(595.0 * 595.0 * 0.5 * (2.0 * M_PI / 720.0));
    const int ir = 511 - iq, jr = 511 - jq;
    unsafeAtomicAdd(&out[iq * NXY + jq], acc0 * SC);   // P0 = (iq, jq)
    unsafeAtomicAdd(&out[jq * NXY + ir], acc1 * SC);   // P1 = (jq, 511-iq)
    unsafeAtomicAdd(&out[ir * NXY + jr], acc2 * SC);   // P2 = (511-iq, 511-jq)
    unsafeAtomicAdd(&out[jr * NXY + iq], acc3 * SC);   // P3 = (511-jq, iq)
}

extern "C" void kernel_launch(void* const* d_in, const int* in_sizes, int n_in,
                              void* d_out, int out_size, void* d_ws, size_t ws_size,
                              hipStream_t stream) {
    const float* sino = (const float*)d_in[0];
    float* out = (float*)d_out;
    float* Q = (float*)d_ws;                                // 720*768*4 = 2,211,840 B
    float4* trig = (float4*)((char*)d_ws + (size_t)NV * NUP * sizeof(float));
    float* swI = (float*)((char*)trig + (size_t)NV * sizeof(float4));  // 180*368*8*4 B

    prep_kernel<<<720, 368, 0, stream>>>(sino, swI, trig, out);
    filter_kernel<<<720, 512, 0, stream>>>(swI, Q);
    bp_kernel<<<4096, 256, 0, stream>>>(Q, trig, out);
}